// Round 7
// baseline (754.288 us; speedup 1.0000x reference)
//
#include <hip/hip_runtime.h>

#define NN 100000
#define NE 1600000
#define HD 128
#define IND 20
#define LNEPS 1e-5f
#define NLIST 100128   // 3129 blocks * 32
#define NKEY 400000    // (node<<2)|rel keys (slot 3 unused)
#define NKEYP 400384   // 391 * 1024
#define SCAN_B 391
#define FILL_PASSES 8
#define REGION 12500
#define ASTRIDE 260    // A-tile row stride in 32-bit words (520 bf16)
#define CNT_B 2048
#define WCAT_B 512
#define ENC_B 3129

typedef unsigned int uint32;
typedef unsigned short ushort16;
typedef __attribute__((ext_vector_type(8))) short bf16x8;
typedef __attribute__((ext_vector_type(4))) float f32x4;
typedef __attribute__((ext_vector_type(2))) float f32x2;

__device__ __forceinline__ ushort16 f2bf(float f) {
    uint32 u = __float_as_uint(f);
    u += 0x7fffu + ((u >> 16) & 1u);   // round-to-nearest-even
    return (ushort16)(u >> 16);
}
__device__ __forceinline__ float bf2f1(ushort16 h) {
    return __uint_as_float(((uint32)h) << 16);
}
__device__ __forceinline__ uint32 pack2bf(float2 v) {
    return (uint32)f2bf(v.x) | ((uint32)f2bf(v.y) << 16);
}

// ---------------- small setup kernels ----------------

__global__ __launch_bounds__(256) void k_hist(const int* __restrict__ nt, int* misc) {
    int i = blockIdx.x * blockDim.x + threadIdx.x;
    int st = gridDim.x * blockDim.x;
    int lane = threadIdx.x & 63;
    for (int n = i; n < NN; n += st) {
        int t = nt[n];
#pragma unroll
        for (int tt = 0; tt < 4; tt++) {
            unsigned long long m = __ballot(t == tt);
            if (t == tt && lane == (__ffsll((unsigned long long)m) - 1))
                atomicAdd(&misc[tt], (int)__popcll(m));
        }
    }
}

__global__ void k_nodebase(int* misc) {
    if (threadIdx.x == 0) {
        int base = 0;
        for (int t = 0; t < 4; t++) { misc[4 + t] = base; base += (misc[t] + 31) & ~31; }
    }
}

__global__ __launch_bounds__(256) void k_fill_n(const int* __restrict__ nt,
                                                int* misc, unsigned* nodelist) {
    int i = blockIdx.x * blockDim.x + threadIdx.x;
    int st = gridDim.x * blockDim.x;
    int lane = threadIdx.x & 63;
    int bases[4] = {misc[4], misc[5], misc[6], misc[7]};
    for (int n = i; n < NN; n += st) {
        int t = nt[n];
#pragma unroll
        for (int tt = 0; tt < 4; tt++) {
            unsigned long long m = __ballot(t == tt);
            if (t == tt) {
                int leader = __ffsll((unsigned long long)m) - 1;
                int base = 0;
                if (lane == leader) base = atomicAdd(&misc[8 + tt], (int)__popcll(m));
                base = __shfl(base, leader);
                int prefix = (int)__popcll(m & (((unsigned long long)1 << lane) - 1));
                nodelist[bases[tt] + base + prefix] = (unsigned)n | ((unsigned)tt << 17);
            }
        }
    }
}

// ---------------- merged: edge-count | weight-pack | encoder ----------------

#define FMA16(A, v0, v1, v2, v3, w)                                       \
    A[0] += v0.x * w; A[1] += v0.y * w; A[2] += v0.z * w; A[3] += v0.w * w; \
    A[4] += v1.x * w; A[5] += v1.y * w; A[6] += v1.z * w; A[7] += v1.w * w; \
    A[8] += v2.x * w; A[9] += v2.y * w; A[10] += v2.z * w; A[11] += v2.w * w; \
    A[12] += v3.x * w; A[13] += v3.y * w; A[14] += v3.z * w; A[15] += v3.w * w;

__global__ __launch_bounds__(256) void k_big(
        const int* __restrict__ ei, const int* __restrict__ et,
        int* cnt, int* __restrict__ rank,
        const unsigned* __restrict__ nodelist, const int* __restrict__ z,
        const float* __restrict__ sd, const float* __restrict__ df,
        const float* __restrict__ cond, const float* __restrict__ mult,
        const float* __restrict__ z_embed,
        const float* __restrict__ W1, const float* __restrict__ b1,
        const float* __restrict__ W2, const float* __restrict__ b2,
        unsigned char* __restrict__ xout,
        const float* __restrict__ rel_W, const float* __restrict__ lin_W,
        ushort16* __restrict__ Wbh, ushort16* __restrict__ Wbl) {
    __shared__ float raw[32][20];
    __shared__ float h1[128][36];
    __shared__ unsigned ent[32];
    int bid = blockIdx.x;
    int tid = threadIdx.x;

    if (bid < CNT_B) {
        // ---- per-(dst,rel) edge count + rank ----
        int i = bid * 256 + tid;
        int st = CNT_B * 256;
        for (int e = i; e < NE; e += st) {
            int key = (ei[NE + e] << 2) | et[e];
            rank[e] = atomicAdd(&cnt[key], 1);
        }
        return;
    }
    bid -= CNT_B;
    if (bid < WCAT_B) {
        // ---- weights -> bf16 B-fragment hi/lo ----
        int idx = bid * 256 + tid;     // exactly 2*512*128
        int j = idx & 7;
        int lane = (idx >> 3) & 63;
        int ntile = (idx >> 9) & 7;
        int kt = (idx >> 12) & 15;
        int l = (idx >> 16) & 1;
        int k = kt * 32 + ((lane >> 4) * 8) + j;
        int n = ntile * 16 + (lane & 15);
        float v;
        if (k < 384) v = rel_W[((l * 3 + (k >> 7)) * HD + (k & 127)) * HD + n];
        else         v = lin_W[(l * HD + (k - 384)) * HD + n];
        ushort16 hi = f2bf(v);
        Wbh[idx] = hi;
        Wbl[idx] = f2bf(v - bf2f1(hi));
        return;
    }
    bid -= WCAT_B;

    // ---- encoder: 32 same-type nodes per block ----
    int base = bid * 32;
    if (tid < 32) ent[tid] = nodelist[base + tid];
    __syncthreads();
    if (ent[0] == 0xFFFFFFFFu) return;
    int type = (int)(ent[0] >> 17);

    for (int idx = tid; idx < 32 * 20; idx += 256) {
        int nl = idx / 20, f = idx - nl * 20;
        unsigned e = ent[nl];
        float v = 0.f;
        if (e != 0xFFFFFFFFu) {
            int node = (int)(e & 0x1FFFF);
            if (f < 16)      v = z_embed[z[node] * 16 + f];
            else if (f == 16) v = sd[node];
            else if (f == 17) v = df[node];
            else if (f == 18) v = cond[node];
            else              v = mult[node];
        }
        raw[nl][f] = v;
    }
    __syncthreads();

    int j = tid & 127, n0 = (tid >> 7) * 16;
    const float* W1t = W1 + type * IND * HD;
    const float* W2t = W2 + type * HD * HD;

    float acc[16];
#pragma unroll
    for (int i = 0; i < 16; i++) acc[i] = 0.f;
    for (int k = 0; k < IND; k++) {
        float w = W1t[k * HD + j];
#pragma unroll
        for (int i = 0; i < 16; i++) acc[i] += raw[n0 + i][k] * w;
    }
    float bb = b1[type * HD + j];
#pragma unroll
    for (int i = 0; i < 16; i++) h1[j][n0 + i] = fmaxf(acc[i] + bb, 0.f);
    __syncthreads();

#pragma unroll
    for (int i = 0; i < 16; i++) acc[i] = 0.f;
    for (int k = 0; k < HD; k++) {
        float w = W2t[k * HD + j];
        const float4* hp = (const float4*)&h1[k][n0];
        float4 v0 = hp[0], v1 = hp[1], v2 = hp[2], v3 = hp[3];
        FMA16(acc, v0, v1, v2, v3, w)
    }
    float b2v = b2[type * HD + j];
#pragma unroll
    for (int i = 0; i < 16; i++) {
        unsigned e = ent[n0 + i];
        if (e != 0xFFFFFFFFu) {
            int node = (int)(e & 0x1FFFF);
            float vv = acc[i] + b2v;
            int pk = __builtin_amdgcn_cvt_pk_fp8_f32(vv, vv, 0, false);
            xout[(size_t)node * HD + j] = (unsigned char)(pk & 0xff);
        }
    }
}

// ---------------- scans over 400k (dst,rel) keys ----------------

__global__ __launch_bounds__(1024) void k_scan1(const int* cnt, int* off, int* bsum) {
    __shared__ int s[1024];
    int tid = threadIdx.x;
    int i = blockIdx.x * 1024 + tid;
    int v = (i < NKEY) ? cnt[i] : 0;
    s[tid] = v;
    __syncthreads();
    for (int o = 1; o < 1024; o <<= 1) {
        int t = (tid >= o) ? s[tid - o] : 0;
        __syncthreads();
        s[tid] += t;
        __syncthreads();
    }
    off[i] = s[tid] - v;
    if (tid == 1023) bsum[blockIdx.x] = s[1023];
}

__global__ __launch_bounds__(512) void k_scan2(int* bsum) {
    __shared__ int s[512];
    int tid = threadIdx.x;
    int v = (tid < SCAN_B) ? bsum[tid] : 0;
    s[tid] = v;
    __syncthreads();
    for (int o = 1; o < 512; o <<= 1) {
        int t = (tid >= o) ? s[tid - o] : 0;
        __syncthreads();
        s[tid] += t;
        __syncthreads();
    }
    if (tid < SCAN_B) bsum[tid] = s[tid] - v;
}

__global__ __launch_bounds__(1024) void k_scan3(int* off, const int* bsum) {
    int i = blockIdx.x * 1024 + threadIdx.x;
    off[i] += bsum[blockIdx.x];
}

// ---------------- atomic-free windowed scatter (keys monotone in dst) ----------------

__global__ __launch_bounds__(256) void k_fill_e(const int* __restrict__ ei,
                                                const int* __restrict__ et,
                                                const int* __restrict__ off,
                                                const int* __restrict__ rank,
                                                unsigned* __restrict__ packed) {
    int i = blockIdx.x * blockDim.x + threadIdx.x;
    int st = gridDim.x * blockDim.x;
    for (int p = 0; p < FILL_PASSES; p++) {
        int lo = p * REGION;
        for (int e = i; e < NE; e += st) {
            int d = ei[NE + e];
            if ((unsigned)(d - lo) < (unsigned)REGION) {
                int key = (d << 2) | et[e];
                packed[off[key] + rank[e]] = (unsigned)ei[e];
            }
        }
    }
}

// ---------------- fused layer: fp8 gather-agg -> bf16 A-tile -> MFMA -> LN -> fp8 out ----------------

__global__ __launch_bounds__(256) void k_fused(
        const ushort16* __restrict__ x,        // fp8 e4m3, 2 features per ushort, row stride 64
        const unsigned* __restrict__ packed,   // src-only, (dst,rel)-sorted
        const int* __restrict__ off,
        const ushort16* __restrict__ Wbh, const ushort16* __restrict__ Wbl,
        const float* __restrict__ lb, const float* __restrict__ g,
        const float* __restrict__ bta, unsigned char* __restrict__ xout) {
    __shared__ uint32 Alds[32 * ASTRIDE];   // bf16 A-tile [32][520]; aliased as hlds [32][132] f32
    __shared__ float stat[32][2];
    __shared__ float gl[HD], bl[HD], ll[HD];
    int tid = threadIdx.x;
    int lane = tid & 63;
    int wv = tid >> 6;
    int nb = blockIdx.x * 32;
    if (tid < HD) { gl[tid] = g[tid]; bl[tid] = bta[tid]; ll[tid] = lb[tid]; }

    // ---- phase A: rel-segmented aggregation (no selects), fp8 gathers ----
#pragma unroll
    for (int i = 0; i < 8; i++) {
        int node = nb + wv * 8 + i;
        int n4 = node << 2;
        int b0 = __builtin_amdgcn_readfirstlane(off[n4]);
        int b1 = __builtin_amdgcn_readfirstlane(off[n4 + 1]);
        int b2 = __builtin_amdgcn_readfirstlane(off[n4 + 2]);
        int b3 = __builtin_amdgcn_readfirstlane(off[n4 + 3]);
        int deg = b3 - b0;
        float id = 1.0f / (float)(deg > 0 ? deg : 1);
        uint32* ar = Alds + (wv * 8 + i) * ASTRIDE;
        int bnd[4] = {b0, b1, b2, b3};
#pragma unroll
        for (int r = 0; r < 3; r++) {
            int s0 = bnd[r], s1 = bnd[r + 1];
            float ax = 0.f, ay = 0.f;
            int e = s0;
            for (; e + 4 <= s1; e += 4) {
                unsigned q0 = packed[e], q1 = packed[e + 1];
                unsigned q2 = packed[e + 2], q3 = packed[e + 3];
                int u0 = x[(size_t)q0 * 64 + lane];
                int u1 = x[(size_t)q1 * 64 + lane];
                int u2 = x[(size_t)q2 * 64 + lane];
                int u3 = x[(size_t)q3 * 64 + lane];
                f32x2 v0 = __builtin_amdgcn_cvt_pk_f32_fp8(u0, false);
                f32x2 v1 = __builtin_amdgcn_cvt_pk_f32_fp8(u1, false);
                f32x2 v2 = __builtin_amdgcn_cvt_pk_f32_fp8(u2, false);
                f32x2 v3 = __builtin_amdgcn_cvt_pk_f32_fp8(u3, false);
                ax += v0.x + v1.x; ay += v0.y + v1.y;
                ax += v2.x + v3.x; ay += v2.y + v3.y;
            }
            for (; e < s1; e++) {
                int u = x[(size_t)packed[e] * 64 + lane];
                f32x2 v = __builtin_amdgcn_cvt_pk_f32_fp8(u, false);
                ax += v.x; ay += v.y;
            }
            float2 sv = {ax * id, ay * id};
            ar[r * 64 + lane] = pack2bf(sv);
        }
        int us = x[(size_t)node * 64 + lane];
        f32x2 vs = __builtin_amdgcn_cvt_pk_f32_fp8(us, false);
        float2 sv = {vs.x, vs.y};
        ar[192 + lane] = pack2bf(sv);
    }
    __syncthreads();

    // ---- phase B: MFMA GEMM (W = Whi + Wlo) ----
    f32x4 acc00 = {0.f, 0.f, 0.f, 0.f}, acc01 = acc00, acc10 = acc00, acc11 = acc00;
    int mrow0 = (lane & 15);
    int mrow1 = 16 + (lane & 15);
    int q4 = (lane >> 4) * 4;
    const bf16x8* wbh = (const bf16x8*)Wbh;
    const bf16x8* wbl = (const bf16x8*)Wbl;
    int nt0 = 2 * wv, nt1 = 2 * wv + 1;

#pragma unroll 4
    for (int kt = 0; kt < 16; kt++) {
        bf16x8 af0 = *(const bf16x8*)&Alds[mrow0 * ASTRIDE + kt * 16 + q4];
        bf16x8 af1 = *(const bf16x8*)&Alds[mrow1 * ASTRIDE + kt * 16 + q4];
        bf16x8 bh0 = wbh[(kt * 8 + nt0) * 64 + lane];
        bf16x8 bh1 = wbh[(kt * 8 + nt1) * 64 + lane];
        bf16x8 bl0 = wbl[(kt * 8 + nt0) * 64 + lane];
        bf16x8 bl1 = wbl[(kt * 8 + nt1) * 64 + lane];
        acc00 = __builtin_amdgcn_mfma_f32_16x16x32_bf16(af0, bh0, acc00, 0, 0, 0);
        acc01 = __builtin_amdgcn_mfma_f32_16x16x32_bf16(af0, bh1, acc01, 0, 0, 0);
        acc10 = __builtin_amdgcn_mfma_f32_16x16x32_bf16(af1, bh0, acc10, 0, 0, 0);
        acc11 = __builtin_amdgcn_mfma_f32_16x16x32_bf16(af1, bh1, acc11, 0, 0, 0);
        acc00 = __builtin_amdgcn_mfma_f32_16x16x32_bf16(af0, bl0, acc00, 0, 0, 0);
        acc01 = __builtin_amdgcn_mfma_f32_16x16x32_bf16(af0, bl1, acc01, 0, 0, 0);
        acc10 = __builtin_amdgcn_mfma_f32_16x16x32_bf16(af1, bl0, acc10, 0, 0, 0);
        acc11 = __builtin_amdgcn_mfma_f32_16x16x32_bf16(af1, bl1, acc11, 0, 0, 0);
    }
    __syncthreads();   // A-tile reads done; alias as hlds

    // ---- bias into LDS for LN stats ----
    float* hlds = (float*)Alds;            // [32][132]
    int n0 = nt0 * 16 + (lane & 15);
    int n1 = n0 + 16;
    float bj0 = ll[n0], bj1 = ll[n1];
    int rbase = (lane >> 4) * 4;
#pragma unroll
    for (int r = 0; r < 4; r++) {
        hlds[(rbase + r) * 132 + n0]      = acc00[r] + bj0;
        hlds[(rbase + r) * 132 + n1]      = acc01[r] + bj1;
        hlds[(16 + rbase + r) * 132 + n0] = acc10[r] + bj0;
        hlds[(16 + rbase + r) * 132 + n1] = acc11[r] + bj1;
    }
    __syncthreads();

    {
        int node = tid >> 3, l8 = tid & 7;
        float s = 0.f, ss = 0.f;
#pragma unroll
        for (int i = 0; i < 16; i++) {
            float v = hlds[node * 132 + l8 + 8 * i];
            s += v; ss += v * v;
        }
        for (int d = 4; d >= 1; d >>= 1) {
            s += __shfl_down(s, d, 8);
            ss += __shfl_down(ss, d, 8);
        }
        if (l8 == 0) {
            float mu = s * (1.f / 128.f);
            float var = ss * (1.f / 128.f) - mu * mu;
            stat[node][0] = mu;
            stat[node][1] = rsqrtf(var + LNEPS);
        }
    }
    __syncthreads();

    // ---- LN epilogue + fp8 repack (16B per thread, coalesced) ----
    {
        int node = tid >> 3, q8 = tid & 7;
        float mu = stat[node][0], rs = stat[node][1];
        const float* hr = hlds + node * 132 + q8 * 16;
        int w[4];
#pragma unroll
        for (int p = 0; p < 4; p++) {
            int f = q8 * 16 + p * 4;
            float v0 = (hr[p * 4 + 0] - mu) * rs * gl[f + 0] + bl[f + 0];
            float v1 = (hr[p * 4 + 1] - mu) * rs * gl[f + 1] + bl[f + 1];
            float v2 = (hr[p * 4 + 2] - mu) * rs * gl[f + 2] + bl[f + 2];
            float v3 = (hr[p * 4 + 3] - mu) * rs * gl[f + 3] + bl[f + 3];
            int pk = __builtin_amdgcn_cvt_pk_fp8_f32(v0, v1, 0, false);
            pk = __builtin_amdgcn_cvt_pk_fp8_f32(v2, v3, pk, true);
            w[p] = pk;
        }
        int4 o4 = make_int4(w[0], w[1], w[2], w[3]);
        *(int4*)(xout + (size_t)(nb + node) * 128 + q8 * 16) = o4;
    }
}

// ---------------- pooling + regressor ----------------

__global__ __launch_bounds__(256) void k_pool(const ushort16* __restrict__ x,
                                              const float* regW, const float* reg_b,
                                              float* out) {
    int tid = threadIdx.x;
    int p = tid & 63;
    float sx = 0.f, sy = 0.f;
    int row = blockIdx.x * 4 + (tid >> 6);
    for (; row < NN; row += gridDim.x * 4) {
        int u = x[(size_t)row * 64 + p];
        f32x2 v = __builtin_amdgcn_cvt_pk_f32_fp8(u, false);
        sx += v.x; sy += v.y;
    }
    float s = sx * regW[2 * p] + sy * regW[2 * p + 1];
    for (int d = 32; d >= 1; d >>= 1) s += __shfl_down(s, d);
    __shared__ float red[4];
    if ((tid & 63) == 0) red[tid >> 6] = s;
    __syncthreads();
    if (tid == 0) {
        float t = (red[0] + red[1] + red[2] + red[3]) * (1.0f / (float)NN);
        if (blockIdx.x == 0) t += reg_b[0];
        atomicAdd(out, t);
    }
}

// ---------------- launcher ----------------

extern "C" void kernel_launch(void* const* d_in, const int* in_sizes, int n_in,
                              void* d_out, int out_size, void* d_ws, size_t ws_size,
                              hipStream_t stream) {
    const int*   z       = (const int*)d_in[0];
    const float* sd      = (const float*)d_in[1];
    const float* df      = (const float*)d_in[2];
    const float* cond    = (const float*)d_in[3];
    const float* mult    = (const float*)d_in[4];
    const int*   nt      = (const int*)d_in[5];
    const int*   ei      = (const int*)d_in[6];
    const int*   et      = (const int*)d_in[7];
    const float* z_embed = (const float*)d_in[8];
    const float* enc_W1  = (const float*)d_in[9];
    const float* enc_b1  = (const float*)d_in[10];
    const float* enc_W2  = (const float*)d_in[11];
    const float* enc_b2  = (const float*)d_in[12];
    const float* lin_W   = (const float*)d_in[13];
    const float* lin_b   = (const float*)d_in[14];
    const float* rel_W   = (const float*)d_in[15];
    const float* ln_g    = (const float*)d_in[16];
    const float* ln_b    = (const float*)d_in[17];
    const float* reg_W   = (const float*)d_in[18];
    const float* reg_b   = (const float*)d_in[19];
    float* out = (float*)d_out;

    char* p = (char*)d_ws;
    int* cnt        = (int*)p;      p += (size_t)NKEYP * 4;
    int* off        = (int*)p;      p += (size_t)NKEYP * 4;
    int* rank       = (int*)p;      p += (size_t)NE * 4;
    int* bsum       = (int*)p;      p += 512 * 4;
    int* misc       = (int*)p;      p += 16 * 4;
    unsigned* packed   = (unsigned*)p; p += (size_t)NE * 4;
    unsigned* nodelist = (unsigned*)p; p += (size_t)NLIST * 4;
    ushort16* Wbh   = (ushort16*)p; p += (size_t)2 * 512 * 128 * 2;
    ushort16* Wbl   = (ushort16*)p; p += (size_t)2 * 512 * 128 * 2;
    unsigned char* x0 = (unsigned char*)p; p += (size_t)NN * HD;
    unsigned char* x1 = (unsigned char*)p; p += (size_t)NN * HD;

    hipMemsetAsync(cnt, 0, (size_t)NKEY * 4, stream);
    hipMemsetAsync(misc, 0, 64, stream);
    hipMemsetAsync(nodelist, 0xFF, (size_t)NLIST * 4, stream);
    hipMemsetAsync(out, 0, 4, stream);

    k_hist<<<400, 256, 0, stream>>>(nt, misc);
    k_nodebase<<<1, 64, 0, stream>>>(misc);
    k_fill_n<<<400, 256, 0, stream>>>(nt, misc, nodelist);
    k_big<<<CNT_B + WCAT_B + ENC_B, 256, 0, stream>>>(
        ei, et, cnt, rank,
        nodelist, z, sd, df, cond, mult, z_embed,
        enc_W1, enc_b1, enc_W2, enc_b2, x0,
        rel_W, lin_W, Wbh, Wbl);
    k_scan1<<<SCAN_B, 1024, 0, stream>>>(cnt, off, bsum);
    k_scan2<<<1, 512, 0, stream>>>(bsum);
    k_scan3<<<SCAN_B, 1024, 0, stream>>>(off, bsum);
    k_fill_e<<<2048, 256, 0, stream>>>(ei, et, off, rank, packed);

    unsigned char* xin = x0; unsigned char* xo = x1;
    for (int l = 0; l < 2; l++) {
        k_fused<<<NN / 32, 256, 0, stream>>>((const ushort16*)xin, packed, off,
                                             Wbh + (size_t)l * 512 * 128,
                                             Wbl + (size_t)l * 512 * 128,
                                             lin_b + l * HD, ln_g + l * HD, ln_b + l * HD,
                                             xo);
        unsigned char* t = xin; xin = xo; xo = t;
    }
    k_pool<<<256, 256, 0, stream>>>((const ushort16*)xin, reg_W, reg_b, out);
}

// Round 8
// 558.673 us; speedup vs baseline: 1.3501x; 1.3501x over previous
//
#include <hip/hip_runtime.h>

#define NN 100000
#define NE 1600000
#define HD 128
#define IND 20
#define LNEPS 1e-5f
#define NLIST2 400000  // 4 type regions of NN
#define NKEY 400000    // (node<<2)|rel keys (slot 3 unused)
#define NKEYP 400384   // 391 * 1024
#define SCAN_B 391
#define FILL_PASSES 8
#define REGION 12500
#define ASTRIDE 260    // A-tile row stride in 32-bit words (520 bf16)
#define CNT_B 2048
#define WCAT_B 512
#define ENC_B 12500
#define BIG_B 16384

typedef unsigned int uint32;
typedef unsigned short ushort16;
typedef __attribute__((ext_vector_type(8))) short bf16x8;
typedef __attribute__((ext_vector_type(4))) float f32x4;
typedef __attribute__((ext_vector_type(2))) float f32x2;

__device__ __forceinline__ ushort16 f2bf(float f) {
    uint32 u = __float_as_uint(f);
    u += 0x7fffu + ((u >> 16) & 1u);   // round-to-nearest-even
    return (ushort16)(u >> 16);
}
__device__ __forceinline__ float bf2f1(ushort16 h) {
    return __uint_as_float(((uint32)h) << 16);
}
__device__ __forceinline__ uint32 pack2bf(float2 v) {
    return (uint32)f2bf(v.x) | ((uint32)f2bf(v.y) << 16);
}

// ---------------- node list: fixed per-type regions, single kernel ----------------

__global__ __launch_bounds__(256) void k_fill_n(const int* __restrict__ nt,
                                                int* misc, unsigned* nodelist) {
    int i = blockIdx.x * blockDim.x + threadIdx.x;
    int st = gridDim.x * blockDim.x;
    int lane = threadIdx.x & 63;
    for (int n = i; n < NN; n += st) {
        int t = nt[n];
#pragma unroll
        for (int tt = 0; tt < 4; tt++) {
            unsigned long long m = __ballot(t == tt);
            if (t == tt) {
                int leader = __ffsll((unsigned long long)m) - 1;
                int base = 0;
                if (lane == leader) base = atomicAdd(&misc[8 + tt], (int)__popcll(m));
                base = __shfl(base, leader);
                int prefix = (int)__popcll(m & (((unsigned long long)1 << lane) - 1));
                nodelist[tt * NN + base + prefix] = (unsigned)n | ((unsigned)tt << 17);
            }
        }
    }
}

// ---------------- merged: edge-count | weight-pack | encoder (interleaved roles) ----------------

#define FMA16(A, v0, v1, v2, v3, w)                                       \
    A[0] += v0.x * w; A[1] += v0.y * w; A[2] += v0.z * w; A[3] += v0.w * w; \
    A[4] += v1.x * w; A[5] += v1.y * w; A[6] += v1.z * w; A[7] += v1.w * w; \
    A[8] += v2.x * w; A[9] += v2.y * w; A[10] += v2.z * w; A[11] += v2.w * w; \
    A[12] += v3.x * w; A[13] += v3.y * w; A[14] += v3.z * w; A[15] += v3.w * w;

__global__ __launch_bounds__(256) void k_big(
        const int* __restrict__ ei, const int* __restrict__ et,
        int* cnt, int* __restrict__ rank,
        const unsigned* __restrict__ nodelist, const int* __restrict__ z,
        const float* __restrict__ sd, const float* __restrict__ df,
        const float* __restrict__ cond, const float* __restrict__ mult,
        const float* __restrict__ z_embed,
        const float* __restrict__ W1, const float* __restrict__ b1,
        const float* __restrict__ W2, const float* __restrict__ b2,
        unsigned char* __restrict__ xout,
        const float* __restrict__ rel_W, const float* __restrict__ lin_W,
        ushort16* __restrict__ Wbh, ushort16* __restrict__ Wbl) {
    __shared__ float raw[32][20];
    __shared__ float h1[128][36];
    __shared__ unsigned ent[32];
    int bid = blockIdx.x;
    int tid = threadIdx.x;
    int sub = bid & 7;

    if (sub == 0) {
        // ---- per-(dst,rel) edge count + rank (2048 blocks interleaved) ----
        int cb = bid >> 3;
        int i = cb * 256 + tid;
        int st = CNT_B * 256;
        for (int e = i; e < NE; e += st) {
            int key = (ei[NE + e] << 2) | et[e];
            rank[e] = atomicAdd(&cnt[key], 1);
        }
        return;
    }
    int j = (bid >> 3) * 7 + sub - 1;      // 0..14335
    if (j < WCAT_B) {
        // ---- weights -> bf16 B-fragment hi/lo ----
        int idx = j * 256 + tid;           // exactly 2*512*128
        int jj = idx & 7;
        int lane = (idx >> 3) & 63;
        int ntile = (idx >> 9) & 7;
        int kt = (idx >> 12) & 15;
        int l = (idx >> 16) & 1;
        int k = kt * 32 + ((lane >> 4) * 8) + jj;
        int n = ntile * 16 + (lane & 15);
        float v;
        if (k < 384) v = rel_W[((l * 3 + (k >> 7)) * HD + (k & 127)) * HD + n];
        else         v = lin_W[(l * HD + (k - 384)) * HD + n];
        ushort16 hi = f2bf(v);
        Wbh[idx] = hi;
        Wbl[idx] = f2bf(v - bf2f1(hi));
        return;
    }
    j -= WCAT_B;
    if (j >= ENC_B) return;

    // ---- encoder: 32 same-type nodes per block (early-exit on pad blocks) ----
    int base = j * 32;
    if (tid < 32) ent[tid] = nodelist[base + tid];
    __syncthreads();
    if (ent[0] == 0xFFFFFFFFu) return;
    int type = (int)(ent[0] >> 17);

    for (int idx = tid; idx < 32 * 20; idx += 256) {
        int nl = idx / 20, f = idx - nl * 20;
        unsigned e = ent[nl];
        float v = 0.f;
        if (e != 0xFFFFFFFFu) {
            int node = (int)(e & 0x1FFFF);
            if (f < 16)      v = z_embed[z[node] * 16 + f];
            else if (f == 16) v = sd[node];
            else if (f == 17) v = df[node];
            else if (f == 18) v = cond[node];
            else              v = mult[node];
        }
        raw[nl][f] = v;
    }
    __syncthreads();

    int jf = tid & 127, n0 = (tid >> 7) * 16;
    const float* W1t = W1 + type * IND * HD;
    const float* W2t = W2 + type * HD * HD;

    float acc[16];
#pragma unroll
    for (int i = 0; i < 16; i++) acc[i] = 0.f;
    for (int k = 0; k < IND; k++) {
        float w = W1t[k * HD + jf];
#pragma unroll
        for (int i = 0; i < 16; i++) acc[i] += raw[n0 + i][k] * w;
    }
    float bb = b1[type * HD + jf];
#pragma unroll
    for (int i = 0; i < 16; i++) h1[jf][n0 + i] = fmaxf(acc[i] + bb, 0.f);
    __syncthreads();

#pragma unroll
    for (int i = 0; i < 16; i++) acc[i] = 0.f;
    for (int k = 0; k < HD; k++) {
        float w = W2t[k * HD + jf];
        const float4* hp = (const float4*)&h1[k][n0];
        float4 v0 = hp[0], v1 = hp[1], v2 = hp[2], v3 = hp[3];
        FMA16(acc, v0, v1, v2, v3, w)
    }
    float b2v = b2[type * HD + jf];
#pragma unroll
    for (int i = 0; i < 16; i++) {
        unsigned e = ent[n0 + i];
        if (e != 0xFFFFFFFFu) {
            int node = (int)(e & 0x1FFFF);
            float vv = acc[i] + b2v;
            int pk = __builtin_amdgcn_cvt_pk_fp8_f32(vv, vv, 0, false);
            xout[(size_t)node * HD + jf] = (unsigned char)(pk & 0xff);
        }
    }
}

// ---------------- scans over 400k (dst,rel) keys ----------------

__global__ __launch_bounds__(1024) void k_scan1(const int* cnt, int* off, int* bsum) {
    __shared__ int s[1024];
    int tid = threadIdx.x;
    int i = blockIdx.x * 1024 + tid;
    int v = (i < NKEY) ? cnt[i] : 0;
    s[tid] = v;
    __syncthreads();
    for (int o = 1; o < 1024; o <<= 1) {
        int t = (tid >= o) ? s[tid - o] : 0;
        __syncthreads();
        s[tid] += t;
        __syncthreads();
    }
    off[i] = s[tid] - v;
    if (tid == 1023) bsum[blockIdx.x] = s[1023];
}

__global__ __launch_bounds__(512) void k_scan2(int* bsum) {
    __shared__ int s[512];
    int tid = threadIdx.x;
    int v = (tid < SCAN_B) ? bsum[tid] : 0;
    s[tid] = v;
    __syncthreads();
    for (int o = 1; o < 512; o <<= 1) {
        int t = (tid >= o) ? s[tid - o] : 0;
        __syncthreads();
        s[tid] += t;
        __syncthreads();
    }
    if (tid < SCAN_B) bsum[tid] = s[tid] - v;
}

__global__ __launch_bounds__(1024) void k_scan3(int* off, const int* bsum) {
    int i = blockIdx.x * 1024 + threadIdx.x;
    off[i] += bsum[blockIdx.x];
}

// ---------------- atomic-free windowed scatter (keys monotone in dst) ----------------

__global__ __launch_bounds__(256) void k_fill_e(const int* __restrict__ ei,
                                                const int* __restrict__ et,
                                                const int* __restrict__ off,
                                                const int* __restrict__ rank,
                                                unsigned* __restrict__ packed) {
    int i = blockIdx.x * blockDim.x + threadIdx.x;
    int st = gridDim.x * blockDim.x;
    for (int p = 0; p < FILL_PASSES; p++) {
        int lo = p * REGION;
        for (int e = i; e < NE; e += st) {
            int d = ei[NE + e];
            if ((unsigned)(d - lo) < (unsigned)REGION) {
                int key = (d << 2) | et[e];
                packed[off[key] + rank[e]] = (unsigned)ei[e];
            }
        }
    }
}

// ---------------- fused layer: fp8 gather-agg -> bf16 A-tile -> MFMA -> LN -> fp8 out ----------------
// 512 threads = 8 waves; wave w aggregates 4 nodes via a flat clamped 8-wide
// edge loop (always 8 gathers in flight); relation picked by wave-uniform
// index comparisons against segment boundaries.

#define EDGE_ACC(ek, v)                                                     \
    a0x += ((ek) < bb1) ? (v).x : 0.f; a0y += ((ek) < bb1) ? (v).y : 0.f;   \
    a1x += ((ek) >= bb1 && (ek) < bb2) ? (v).x : 0.f;                       \
    a1y += ((ek) >= bb1 && (ek) < bb2) ? (v).y : 0.f;                       \
    a2x += ((ek) >= bb2 && (ek) < bb3) ? (v).x : 0.f;                       \
    a2y += ((ek) >= bb2 && (ek) < bb3) ? (v).y : 0.f;

__global__ __launch_bounds__(512, 6) void k_fused(
        const ushort16* __restrict__ x,        // fp8 e4m3, 2 features per ushort, row stride 64
        const unsigned* __restrict__ packed,   // src-only, (dst,rel)-sorted
        const int* __restrict__ off,
        const ushort16* __restrict__ Wbh, const ushort16* __restrict__ Wbl,
        const float* __restrict__ lb, const float* __restrict__ g,
        const float* __restrict__ bta, unsigned char* __restrict__ xout) {
    __shared__ uint32 Alds[32 * ASTRIDE];   // bf16 A-tile [32][520]; aliased as hlds [32][132] f32
    __shared__ float stat[32][2];
    int tid = threadIdx.x;
    int lane = tid & 63;
    int wv = tid >> 6;                     // 0..7
    int nb = blockIdx.x * 32;

    // all boundaries for this wave's 4 nodes in one vector load (16 ints used)
    int bv = off[((nb + wv * 4) << 2) + lane];

    // ---- phase A: flat 8-wide clamped edge loop per node ----
#pragma unroll
    for (int i = 0; i < 4; i++) {
        int node = nb + wv * 4 + i;
        int bb0 = __builtin_amdgcn_readlane(bv, 4 * i);
        int bb1 = __builtin_amdgcn_readlane(bv, 4 * i + 1);
        int bb2 = __builtin_amdgcn_readlane(bv, 4 * i + 2);
        int bb3 = __builtin_amdgcn_readlane(bv, 4 * i + 3);
        int deg = bb3 - bb0;
        float id = 1.0f / (float)(deg > 0 ? deg : 1);
        int us = x[(size_t)node * 64 + lane];           // self row (early issue)
        float a0x = 0.f, a0y = 0.f, a1x = 0.f, a1y = 0.f, a2x = 0.f, a2y = 0.f;
        int last = bb3 - 1;
        for (int e = bb0; e < bb3; e += 8) {
            unsigned q0 = packed[e];
            unsigned q1 = packed[e + 1 > last ? last : e + 1];
            unsigned q2 = packed[e + 2 > last ? last : e + 2];
            unsigned q3 = packed[e + 3 > last ? last : e + 3];
            unsigned q4 = packed[e + 4 > last ? last : e + 4];
            unsigned q5 = packed[e + 5 > last ? last : e + 5];
            unsigned q6 = packed[e + 6 > last ? last : e + 6];
            unsigned q7 = packed[e + 7 > last ? last : e + 7];
            int u0 = x[(size_t)q0 * 64 + lane];
            int u1 = x[(size_t)q1 * 64 + lane];
            int u2 = x[(size_t)q2 * 64 + lane];
            int u3 = x[(size_t)q3 * 64 + lane];
            int u4 = x[(size_t)q4 * 64 + lane];
            int u5 = x[(size_t)q5 * 64 + lane];
            int u6 = x[(size_t)q6 * 64 + lane];
            int u7 = x[(size_t)q7 * 64 + lane];
            f32x2 v0 = __builtin_amdgcn_cvt_pk_f32_fp8(u0, false);
            f32x2 v1 = __builtin_amdgcn_cvt_pk_f32_fp8(u1, false);
            f32x2 v2 = __builtin_amdgcn_cvt_pk_f32_fp8(u2, false);
            f32x2 v3 = __builtin_amdgcn_cvt_pk_f32_fp8(u3, false);
            f32x2 v4 = __builtin_amdgcn_cvt_pk_f32_fp8(u4, false);
            f32x2 v5 = __builtin_amdgcn_cvt_pk_f32_fp8(u5, false);
            f32x2 v6 = __builtin_amdgcn_cvt_pk_f32_fp8(u6, false);
            f32x2 v7 = __builtin_amdgcn_cvt_pk_f32_fp8(u7, false);
            EDGE_ACC(e, v0)     EDGE_ACC(e + 1, v1)
            EDGE_ACC(e + 2, v2) EDGE_ACC(e + 3, v3)
            EDGE_ACC(e + 4, v4) EDGE_ACC(e + 5, v5)
            EDGE_ACC(e + 6, v6) EDGE_ACC(e + 7, v7)
        }
        uint32* ar = Alds + (wv * 4 + i) * ASTRIDE;
        float2 s0 = {a0x * id, a0y * id};
        float2 s1 = {a1x * id, a1y * id};
        float2 s2 = {a2x * id, a2y * id};
        f32x2 vs = __builtin_amdgcn_cvt_pk_f32_fp8(us, false);
        float2 s3 = {vs.x, vs.y};
        ar[lane]       = pack2bf(s0);
        ar[64 + lane]  = pack2bf(s1);
        ar[128 + lane] = pack2bf(s2);
        ar[192 + lane] = pack2bf(s3);
    }
    __syncthreads();

    // ---- phase B: MFMA GEMM (W = Whi + Wlo); wave w: n-tile w, m-tiles {0,1} ----
    f32x4 acc00 = {0.f, 0.f, 0.f, 0.f}, acc10 = acc00;
    int mrow0 = (lane & 15);
    int mrow1 = 16 + (lane & 15);
    int q4 = (lane >> 4) * 4;
    const bf16x8* wbh = (const bf16x8*)Wbh;
    const bf16x8* wbl = (const bf16x8*)Wbl;

#pragma unroll 4
    for (int kt = 0; kt < 16; kt++) {
        bf16x8 af0 = *(const bf16x8*)&Alds[mrow0 * ASTRIDE + kt * 16 + q4];
        bf16x8 af1 = *(const bf16x8*)&Alds[mrow1 * ASTRIDE + kt * 16 + q4];
        bf16x8 bh0 = wbh[(kt * 8 + wv) * 64 + lane];
        bf16x8 bl0 = wbl[(kt * 8 + wv) * 64 + lane];
        acc00 = __builtin_amdgcn_mfma_f32_16x16x32_bf16(af0, bh0, acc00, 0, 0, 0);
        acc10 = __builtin_amdgcn_mfma_f32_16x16x32_bf16(af1, bh0, acc10, 0, 0, 0);
        acc00 = __builtin_amdgcn_mfma_f32_16x16x32_bf16(af0, bl0, acc00, 0, 0, 0);
        acc10 = __builtin_amdgcn_mfma_f32_16x16x32_bf16(af1, bl0, acc10, 0, 0, 0);
    }
    __syncthreads();   // A-tile reads done; alias as hlds

    // ---- bias into LDS for LN stats ----
    float* hlds = (float*)Alds;            // [32][132]
    int n0 = wv * 16 + (lane & 15);
    float bj0 = lb[n0];
    int rbase = (lane >> 4) * 4;
#pragma unroll
    for (int r = 0; r < 4; r++) {
        hlds[(rbase + r) * 132 + n0]      = acc00[r] + bj0;
        hlds[(16 + rbase + r) * 132 + n0] = acc10[r] + bj0;
    }
    __syncthreads();

    {
        int node = tid >> 4, l16 = tid & 15;
        float s = 0.f, ss = 0.f;
#pragma unroll
        for (int i = 0; i < 8; i++) {
            float v = hlds[node * 132 + l16 + 16 * i];
            s += v; ss += v * v;
        }
        for (int d = 8; d >= 1; d >>= 1) {
            s += __shfl_down(s, d, 16);
            ss += __shfl_down(ss, d, 16);
        }
        if (l16 == 0) {
            float mu = s * (1.f / 128.f);
            float var = ss * (1.f / 128.f) - mu * mu;
            stat[node][0] = mu;
            stat[node][1] = rsqrtf(var + LNEPS);
        }
    }
    __syncthreads();

    // ---- LN epilogue + fp8 repack (8B per thread, coalesced) ----
    {
        int node = tid >> 4, q16 = tid & 15;
        float mu = stat[node][0], rs = stat[node][1];
        const float* hr = hlds + node * 132 + q16 * 8;
        int w[2];
#pragma unroll
        for (int p = 0; p < 2; p++) {
            int f = q16 * 8 + p * 4;
            float v0 = (hr[p * 4 + 0] - mu) * rs * g[f + 0] + bta[f + 0];
            float v1 = (hr[p * 4 + 1] - mu) * rs * g[f + 1] + bta[f + 1];
            float v2 = (hr[p * 4 + 2] - mu) * rs * g[f + 2] + bta[f + 2];
            float v3 = (hr[p * 4 + 3] - mu) * rs * g[f + 3] + bta[f + 3];
            int pk = __builtin_amdgcn_cvt_pk_fp8_f32(v0, v1, 0, false);
            pk = __builtin_amdgcn_cvt_pk_fp8_f32(v2, v3, pk, true);
            w[p] = pk;
        }
        *(int2*)(xout + (size_t)(nb + node) * 128 + q16 * 8) = make_int2(w[0], w[1]);
    }
}

// ---------------- pooling + regressor ----------------

__global__ __launch_bounds__(256) void k_pool(const ushort16* __restrict__ x,
                                              const float* regW, const float* reg_b,
                                              float* out) {
    int tid = threadIdx.x;
    int p = tid & 63;
    float sx = 0.f, sy = 0.f;
    int row = blockIdx.x * 4 + (tid >> 6);
    for (; row < NN; row += gridDim.x * 4) {
        int u = x[(size_t)row * 64 + p];
        f32x2 v = __builtin_amdgcn_cvt_pk_f32_fp8(u, false);
        sx += v.x; sy += v.y;
    }
    float s = sx * regW[2 * p] + sy * regW[2 * p + 1];
    for (int d = 32; d >= 1; d >>= 1) s += __shfl_down(s, d);
    __shared__ float red[4];
    if ((tid & 63) == 0) red[tid >> 6] = s;
    __syncthreads();
    if (tid == 0) {
        float t = (red[0] + red[1] + red[2] + red[3]) * (1.0f / (float)NN);
        if (blockIdx.x == 0) t += reg_b[0];
        atomicAdd(out, t);
    }
}

// ---------------- launcher ----------------

extern "C" void kernel_launch(void* const* d_in, const int* in_sizes, int n_in,
                              void* d_out, int out_size, void* d_ws, size_t ws_size,
                              hipStream_t stream) {
    const int*   z       = (const int*)d_in[0];
    const float* sd      = (const float*)d_in[1];
    const float* df      = (const float*)d_in[2];
    const float* cond    = (const float*)d_in[3];
    const float* mult    = (const float*)d_in[4];
    const int*   nt      = (const int*)d_in[5];
    const int*   ei      = (const int*)d_in[6];
    const int*   et      = (const int*)d_in[7];
    const float* z_embed = (const float*)d_in[8];
    const float* enc_W1  = (const float*)d_in[9];
    const float* enc_b1  = (const float*)d_in[10];
    const float* enc_W2  = (const float*)d_in[11];
    const float* enc_b2  = (const float*)d_in[12];
    const float* lin_W   = (const float*)d_in[13];
    const float* lin_b   = (const float*)d_in[14];
    const float* rel_W   = (const float*)d_in[15];
    const float* ln_g    = (const float*)d_in[16];
    const float* ln_b    = (const float*)d_in[17];
    const float* reg_W   = (const float*)d_in[18];
    const float* reg_b   = (const float*)d_in[19];
    float* out = (float*)d_out;

    char* p = (char*)d_ws;
    int* cnt        = (int*)p;      p += (size_t)NKEYP * 4;
    int* misc       = (int*)p;      p += 16 * 4;           // contiguous with cnt for one memset
    int* off        = (int*)p;      p += (size_t)NKEYP * 4;
    int* rank       = (int*)p;      p += (size_t)NE * 4;
    int* bsum       = (int*)p;      p += 512 * 4;
    unsigned* packed   = (unsigned*)p; p += (size_t)NE * 4;
    unsigned* nodelist = (unsigned*)p; p += (size_t)NLIST2 * 4;
    ushort16* Wbh   = (ushort16*)p; p += (size_t)2 * 512 * 128 * 2;
    ushort16* Wbl   = (ushort16*)p; p += (size_t)2 * 512 * 128 * 2;
    unsigned char* x0 = (unsigned char*)p; p += (size_t)NN * HD;
    unsigned char* x1 = (unsigned char*)p; p += (size_t)NN * HD;

    hipMemsetAsync(cnt, 0, (size_t)NKEYP * 4 + 64, stream);
    hipMemsetAsync(nodelist, 0xFF, (size_t)NLIST2 * 4, stream);
    hipMemsetAsync(out, 0, 4, stream);

    k_fill_n<<<400, 256, 0, stream>>>(nt, misc, nodelist);
    k_big<<<BIG_B, 256, 0, stream>>>(
        ei, et, cnt, rank,
        nodelist, z, sd, df, cond, mult, z_embed,
        enc_W1, enc_b1, enc_W2, enc_b2, x0,
        rel_W, lin_W, Wbh, Wbl);
    k_scan1<<<SCAN_B, 1024, 0, stream>>>(cnt, off, bsum);
    k_scan2<<<1, 512, 0, stream>>>(bsum);
    k_scan3<<<SCAN_B, 1024, 0, stream>>>(off, bsum);
    k_fill_e<<<2048, 256, 0, stream>>>(ei, et, off, rank, packed);

    unsigned char* xin = x0; unsigned char* xo = x1;
    for (int l = 0; l < 2; l++) {
        k_fused<<<NN / 32, 512, 0, stream>>>((const ushort16*)xin, packed, off,
                                             Wbh + (size_t)l * 512 * 128,
                                             Wbl + (size_t)l * 512 * 128,
                                             lin_b + l * HD, ln_g + l * HD, ln_b + l * HD,
                                             xo);
        unsigned char* t = xin; xin = xo; xo = t;
    }
    k_pool<<<256, 256, 0, stream>>>((const ushort16*)xin, reg_W, reg_b, out);
}